// Round 1
// baseline (376.781 us; speedup 1.0000x reference)
//
#include <hip/hip_runtime.h>
#include <hip/hip_bf16.h>
#include <cmath>

namespace {
constexpr int Pn = 128;
constexpr int Hn = 512;
constexpr int Ln = 8192;
constexpr int BS = 8;
// ws byte layout:
//   [0, 2048)             Lam fp32: [0,128) L_re | [128,256) L_im | [256,384) A32_re | [384,512) A32_im
//   [2048, 264192)        Bmat bf16 [256][512]  (rows 0..127 re, 128..255 im)
//   [264192, 526336)      Cmat bf16 [512][256]  (+2*C_re | -2*C_im)
//   [526336, 2623488)     End  fp32 [8][256 chunks][2][128]   (local chunk-end states)
//   [2623488, 4720640)    Carry fp32 [8][256 chunks][2][128]  (exclusive carries)
//   [4720640, ...)        Bu fp32 [NB][8192][256]   ***transposed: [l][p] ***
constexpr size_t OFF_BMAT = 2048;
constexpr size_t OFF_CMAT = 264192;
constexpr size_t OFF_END  = 526336;
constexpr size_t OFF_CAR  = 2623488;
constexpr size_t HEADB    = 4720640;
constexpr size_t SZ_BU = (size_t)256 * Ln * 4;     // 8388608 per batch
}

typedef __attribute__((ext_vector_type(4))) float f32x4;
typedef __attribute__((ext_vector_type(8))) short bf16x8;

static __device__ inline short f2bf(float x) {
  __hip_bfloat16 h = __float2bfloat16(x);
  return *(short*)&h;
}

static __device__ inline void async_copy16(const void* g, void* l) {
  __builtin_amdgcn_global_load_lds(
      (const __attribute__((address_space(1))) unsigned int*)g,
      (__attribute__((address_space(3))) unsigned int*)l, 16, 0, 0);
}

// ---------------------------------------------------------------- precompute
__global__ void precompute_kernel(const float* __restrict__ Lre,
                                  const float* __restrict__ Lim,
                                  const float* __restrict__ Bin,
                                  const float* __restrict__ Cin,
                                  const float* __restrict__ lstep,
                                  float* __restrict__ Lam,
                                  __hip_bfloat16* __restrict__ Bmat,
                                  __hip_bfloat16* __restrict__ Cmat) {
  int tid = blockIdx.x * blockDim.x + threadIdx.x;
  if (tid < 2 * Pn * Hn) {
    int r = tid >> 9;          // row in [0,256)
    int h = tid & (Hn - 1);
    int p = r & (Pn - 1);
    float st = expf(lstep[p]);
    float lr = Lre[p], li = Lim[p];
    float er = expf(lr * st);
    float cr = er * cosf(li * st);
    float ci = er * sinf(li * st);
    float nr = cr - 1.0f, ni = ci;
    float inv = 1.0f / (lr * lr + li * li);
    float wr = (nr * lr + ni * li) * inv;
    float wi = (ni * lr - nr * li) * inv;
    float btr = Bin[(p * Hn + h) * 2 + 0];
    float bti = Bin[(p * Hn + h) * 2 + 1];
    float val = (r < Pn) ? (wr * btr - wi * bti) : (wr * bti + wi * btr);
    Bmat[tid] = __float2bfloat16(val);
  } else if (tid < 4 * Pn * Hn) {
    int j = tid - 2 * Pn * Hn;
    int h = j >> 8;
    int c = j & 255;
    int p = c & (Pn - 1);
    float v = (c < Pn) ? 2.0f * Cin[(h * Pn + p) * 2 + 0]
                       : -2.0f * Cin[(h * Pn + p) * 2 + 1];
    Cmat[j] = __float2bfloat16(v);
  } else if (tid < 4 * Pn * Hn + 512) {
    int j = tid - 4 * Pn * Hn;
    int p = j & 127;
    int sel = j >> 7;   // 0: L_re  1: L_im  2: A32_re  3: A32_im
    float st = expf(lstep[p]);
    float lr = Lre[p], li = Lim[p];
    float sc = (sel < 2) ? st : 32.0f * st;
    float er = expf(lr * sc);
    Lam[(sel >> 1) * 256 + (sel & 1) * 128 + p] =
        (sel & 1) ? er * sinf(li * sc) : er * cosf(li * sc);
  }
}

// ---------------------------------------------------------------- MFMA GEMM1
// Bu_t[bz][l][256] = (Bmat[256][512] @ U[(b0+bz)][512][8192])^T  (transposed store)
__global__ __launch_bounds__(256) void gemm1_kernel(
    const __hip_bfloat16* __restrict__ Amat,  // [256][512]
    const float* __restrict__ U,              // [8][512][8192]
    float* __restrict__ Bu,                   // [NB][8192][256]
    int b0) {
  __shared__ __align__(16) short As[128 * 32];
  __shared__ __align__(16) short Bs[128 * 40];   // stride 40 shorts (80 B, 16B-aligned)
  const int t = threadIdx.x;
  const int lane = t & 63, w = t >> 6;
  const int wm = w >> 1, wn = w & 1;
  const int n0 = blockIdx.x * 128;
  const int m0 = blockIdx.y * 128;
  const int bz = blockIdx.z;
  const float* Ub = U + (size_t)(b0 + bz) * Hn * Ln;

  const int srow = lane >> 2, scol = (lane & 3) * 16;
  const int bn = t & 127, bkg = t >> 7;   // staging: col n, k-group

  f32x4 acc[4][4] = {};
  for (int k0 = 0; k0 < Hn; k0 += 32) {
#pragma unroll
    for (int I2 = 0; I2 < 2; I2++) {
      int I = 2 * w + I2;
      async_copy16((const char*)(Amat + (size_t)(m0 + 16 * I + srow) * Hn + k0) + scol,
                   (char*)As + I * 1024);
    }
#pragma unroll
    for (int p = 0; p < 2; p++) {
      int kb = p * 16 + bkg * 8;
      float v[8];
#pragma unroll
      for (int j = 0; j < 8; j++)
        v[j] = Ub[(size_t)(k0 + kb + j) * Ln + n0 + bn];
      bf16x8 pk;
#pragma unroll
      for (int j = 0; j < 8; j++) pk[j] = f2bf(v[j]);
      *(bf16x8*)&Bs[bn * 40 + kb] = pk;
    }
    __syncthreads();
    bf16x8 af[4], bfr[4];
#pragma unroll
    for (int mt = 0; mt < 4; mt++)
      af[mt] = *(const bf16x8*)&As[(64 * wm + 16 * mt + (lane & 15)) * 32 + (lane >> 4) * 8];
#pragma unroll
    for (int nt = 0; nt < 4; nt++)
      bfr[nt] = *(const bf16x8*)&Bs[(64 * wn + 16 * nt + (lane & 15)) * 40 + (lane >> 4) * 8];
#pragma unroll
    for (int mt = 0; mt < 4; mt++)
#pragma unroll
      for (int nt = 0; nt < 4; nt++)
        acc[mt][nt] = __builtin_amdgcn_mfma_f32_16x16x32_bf16(
            af[mt], bfr[nt], acc[mt][nt], 0, 0, 0);
    __syncthreads();
  }
  // transposed epilogue: acc[mt][nt] is 4 consecutive m for one n -> one f32x4 store
  const int row4 = (lane >> 4) * 4, col = lane & 15;
  float* Bub = Bu + (size_t)bz * Ln * 256;
#pragma unroll
  for (int mt = 0; mt < 4; mt++)
#pragma unroll
    for (int nt = 0; nt < 4; nt++) {
      int n = n0 + 64 * wn + 16 * nt + col;
      int m = m0 + 64 * wm + 16 * mt + row4;
      *(f32x4*)&Bub[(size_t)n * 256 + m] = acc[mt][nt];
    }
}

// ---------------------------------------------------------------- scan phase 1: local chunk ends
// chunk = 32 l's. thread = one complex p. block = 2 chunks x 128 p.
__global__ __launch_bounds__(256) void scan_ends_kernel(const float* __restrict__ Bu,
                                                        const float* __restrict__ Lam,
                                                        float* __restrict__ End) {
  const int bz = blockIdx.y;
  const int t = threadIdx.x;
  const int c = blockIdx.x * 2 + (t >> 7);
  const int p = t & 127;
  const float Ar = Lam[p], Ai = Lam[128 + p];
  const float* base = Bu + ((size_t)bz * Ln + (size_t)c * 32) * 256;
  float br[32], bi[32];
#pragma unroll
  for (int i = 0; i < 32; i++) br[i] = base[(size_t)i * 256 + p];
#pragma unroll
  for (int i = 0; i < 32; i++) bi[i] = base[(size_t)i * 256 + 128 + p];
  float xr = 0.f, xi = 0.f;
#pragma unroll
  for (int i = 0; i < 32; i++) {
    float nr = fmaf(Ar, xr, fmaf(-Ai, xi, br[i]));
    float ni = fmaf(Ar, xi, fmaf(Ai, xr, bi[i]));
    xr = nr; xi = ni;
  }
  float* E = End + ((size_t)bz * 256 + c) * 256;
  E[p] = xr;
  E[128 + p] = xi;
}

// ---------------------------------------------------------------- scan phase 2: carry propagation
// carry_0 = 0 ; carry_{c+1} = A32*carry_c + end_c   (exclusive scan, serial, double-buffered loads)
__global__ __launch_bounds__(128) void carry_kernel(const float* __restrict__ End,
                                                    float* __restrict__ Carry,
                                                    const float* __restrict__ Lam) {
  const int bz = blockIdx.x;
  const int p = threadIdx.x;
  const float a32r = Lam[256 + p], a32i = Lam[384 + p];
  const float* E = End + (size_t)bz * 256 * 256;
  float* C = Carry + (size_t)bz * 256 * 256;
  float xr = 0.f, xi = 0.f;
  float er0[4], ei0[4], er1[4], ei1[4];
#pragma unroll
  for (int q = 0; q < 4; q++) {
    er0[q] = E[(size_t)q * 256 + p];
    ei0[q] = E[(size_t)q * 256 + 128 + p];
  }
  for (int c0 = 0; c0 < 256; c0 += 8) {
#pragma unroll
    for (int q = 0; q < 4; q++) {
      er1[q] = E[(size_t)(c0 + 4 + q) * 256 + p];
      ei1[q] = E[(size_t)(c0 + 4 + q) * 256 + 128 + p];
    }
#pragma unroll
    for (int q = 0; q < 4; q++) {
      C[(size_t)(c0 + q) * 256 + p] = xr;
      C[(size_t)(c0 + q) * 256 + 128 + p] = xi;
      float nr = fmaf(a32r, xr, fmaf(-a32i, xi, er0[q]));
      float ni = fmaf(a32r, xi, fmaf(a32i, xr, ei0[q]));
      xr = nr; xi = ni;
    }
#pragma unroll
    for (int q = 0; q < 4; q++) {
      int cn = c0 + 8 + q;
      if (cn < 256) {
        er0[q] = E[(size_t)cn * 256 + p];
        ei0[q] = E[(size_t)cn * 256 + 128 + p];
      }
    }
#pragma unroll
    for (int q = 0; q < 4; q++) {
      C[(size_t)(c0 + 4 + q) * 256 + p] = xr;
      C[(size_t)(c0 + 4 + q) * 256 + 128 + p] = xi;
      float nr = fmaf(a32r, xr, fmaf(-a32i, xi, er1[q]));
      float ni = fmaf(a32r, xi, fmaf(a32i, xr, ei1[q]));
      xr = nr; xi = ni;
    }
  }
}

// ---------------------------------------------------------------- scan phase 3: seeded local scan, in place
__global__ __launch_bounds__(256) void scan_apply_kernel(float* __restrict__ Bu,
                                                         const float* __restrict__ Lam,
                                                         const float* __restrict__ Carry) {
  const int bz = blockIdx.y;
  const int t = threadIdx.x;
  const int c = blockIdx.x * 2 + (t >> 7);
  const int p = t & 127;
  const float Ar = Lam[p], Ai = Lam[128 + p];
  float* base = Bu + ((size_t)bz * Ln + (size_t)c * 32) * 256;
  const float* Cg = Carry + ((size_t)bz * 256 + c) * 256;
  float br[32], bi[32];
#pragma unroll
  for (int i = 0; i < 32; i++) br[i] = base[(size_t)i * 256 + p];
#pragma unroll
  for (int i = 0; i < 32; i++) bi[i] = base[(size_t)i * 256 + 128 + p];
  float xr = Cg[p], xi = Cg[128 + p];
#pragma unroll
  for (int i = 0; i < 32; i++) {
    float nr = fmaf(Ar, xr, fmaf(-Ai, xi, br[i]));
    float ni = fmaf(Ar, xi, fmaf(Ai, xr, bi[i]));
    xr = nr; xi = ni;
    base[(size_t)i * 256 + p] = nr;
    base[(size_t)i * 256 + 128 + p] = ni;
  }
}

// ---------------------------------------------------------------- MFMA GEMM2 (vectorized k-contiguous staging + fast gelu)
// Out[b][H][L] = gelu( Cmat[512][256] @ Xs^T + D[h]*U[b][h][l] ),  Xs = Bu_t[bz][l][256]
__global__ __launch_bounds__(256) void gemm2_kernel(
    const __hip_bfloat16* __restrict__ Cmat,  // [512][256]
    const float* __restrict__ Xs,             // [NB][8192][256] fp32 (scan output, [l][p])
    const float* __restrict__ U,              // [8][512][8192]
    const float* __restrict__ Dv,             // [512]
    float* __restrict__ Out, int b0) {
  __shared__ __align__(16) short As[128 * 32];
  __shared__ __align__(16) short Bs[128 * 40];
  const int t = threadIdx.x;
  const int lane = t & 63, w = t >> 6;
  const int wm = w >> 1, wn = w & 1;
  const int n0 = blockIdx.x * 128;
  const int m0 = blockIdx.y * 128;
  const int bz = blockIdx.z;
  const int b = b0 + bz;

  const int srow = lane >> 2, scol = (lane & 3) * 16;
  const int bn = t & 127, bkg = t >> 7;
  const float* Xrow = Xs + ((size_t)bz * Ln + n0 + bn) * 256;

  f32x4 acc[4][4] = {};
  for (int k0 = 0; k0 < 256; k0 += 32) {
#pragma unroll
    for (int I2 = 0; I2 < 2; I2++) {
      int I = 2 * w + I2;
      async_copy16((const char*)(Cmat + (size_t)(m0 + 16 * I + srow) * 256 + k0) + scol,
                   (char*)As + I * 1024);
    }
#pragma unroll
    for (int p2 = 0; p2 < 2; p2++) {
      int kb = p2 * 16 + bkg * 8;
      f32x4 x0 = *(const f32x4*)&Xrow[k0 + kb];
      f32x4 x1 = *(const f32x4*)&Xrow[k0 + kb + 4];
      bf16x8 pk;
#pragma unroll
      for (int q = 0; q < 4; q++) { pk[q] = f2bf(x0[q]); pk[4 + q] = f2bf(x1[q]); }
      *(bf16x8*)&Bs[bn * 40 + kb] = pk;
    }
    __syncthreads();
    bf16x8 af[4], bfr[4];
#pragma unroll
    for (int mt = 0; mt < 4; mt++)
      af[mt] = *(const bf16x8*)&As[(64 * wm + 16 * mt + (lane & 15)) * 32 + (lane >> 4) * 8];
#pragma unroll
    for (int nt = 0; nt < 4; nt++)
      bfr[nt] = *(const bf16x8*)&Bs[(64 * wn + 16 * nt + (lane & 15)) * 40 + (lane >> 4) * 8];
#pragma unroll
    for (int mt = 0; mt < 4; mt++)
#pragma unroll
      for (int nt = 0; nt < 4; nt++)
        acc[mt][nt] = __builtin_amdgcn_mfma_f32_16x16x32_bf16(
            af[mt], bfr[nt], acc[mt][nt], 0, 0, 0);
    __syncthreads();
  }
  const int row4 = (lane >> 4) * 4, col = lane & 15;
#pragma unroll
  for (int mt = 0; mt < 4; mt++) {
#pragma unroll
    for (int r = 0; r < 4; r++) {
      int h = m0 + 64 * wm + 16 * mt + row4 + r;
      float dh = Dv[h];
      const float* Urow = U + ((size_t)b * Hn + h) * Ln;
      float* Orow = Out + ((size_t)b * Hn + h) * Ln;
#pragma unroll
      for (int nt = 0; nt < 4; nt++) {
        int n = n0 + 64 * wn + 16 * nt + col;
        float y = acc[mt][nt][r] + dh * Urow[n];
        // tanh-form gelu: y * sigmoid(2*0.7978845608*(y + 0.044715 y^3)), tail-safe
        float u2 = y * (0.7978845608f + 0.0356774081f * y * y);
        Orow[n] = y / (1.0f + __expf(-2.0f * u2));
      }
    }
  }
}

// ---------------------------------------------------------------- launch
extern "C" void kernel_launch(void* const* d_in, const int* in_sizes, int n_in,
                              void* d_out, int out_size, void* d_ws, size_t ws_size,
                              hipStream_t stream) {
  const float* U   = (const float*)d_in[0];
  const float* Lre = (const float*)d_in[1];
  const float* Lim = (const float*)d_in[2];
  const float* Bin = (const float*)d_in[3];
  const float* Cin = (const float*)d_in[4];
  const float* Dv  = (const float*)d_in[5];
  const float* ls  = (const float*)d_in[6];
  float* out = (float*)d_out;

  char* wsb = (char*)d_ws;
  float* Lam = (float*)wsb;
  __hip_bfloat16* Bmat = (__hip_bfloat16*)(wsb + OFF_BMAT);
  __hip_bfloat16* Cmat = (__hip_bfloat16*)(wsb + OFF_CMAT);
  float* End = (float*)(wsb + OFF_END);
  float* Cy  = (float*)(wsb + OFF_CAR);
  float* Bu  = (float*)(wsb + HEADB);

  int NB = 8;
  while (NB > 1 && ws_size < HEADB + (size_t)NB * SZ_BU)
    NB >>= 1;

  precompute_kernel<<<(4 * Pn * Hn + 512 + 255) / 256, 256, 0, stream>>>(
      Lre, Lim, Bin, Cin, ls, Lam, Bmat, Cmat);

  for (int b0 = 0; b0 < BS; b0 += NB) {
    gemm1_kernel<<<dim3(Ln / 128, 2, NB), 256, 0, stream>>>(Bmat, U, Bu, b0);
    scan_ends_kernel<<<dim3(128, NB), 256, 0, stream>>>(Bu, Lam, End);
    carry_kernel<<<dim3(NB), 128, 0, stream>>>(End, Cy, Lam);
    scan_apply_kernel<<<dim3(128, NB), 256, 0, stream>>>(Bu, Lam, Cy);
    gemm2_kernel<<<dim3(Ln / 128, Hn / 128, NB), 256, 0, stream>>>(
        Cmat, Bu, U, Dv, out, b0);
  }
}

// Round 3
// 373.180 us; speedup vs baseline: 1.0096x; 1.0096x over previous
//
#include <hip/hip_runtime.h>
#include <hip/hip_bf16.h>
#include <cmath>

namespace {
constexpr int Pn = 128;
constexpr int Hn = 512;
constexpr int Ln = 8192;
constexpr int BS = 8;
// ws byte layout:
//   [0, 2048)             Lam fp32: [0,128) L_re | [128,256) L_im | [256,384) A32_re | [384,512) A32_im
//   [2048, 264192)        Bmat bf16 [256][512]  (rows 0..127 re, 128..255 im)
//   [264192, 526336)      Cmat bf16 [512][256]  (+2*C_re | -2*C_im)
//   [526336, 2623488)     End  fp32 [8][256 chunks][2][128]   (local chunk-end states)
//   [2623488, 4720640)    Carry fp32 [8][256 chunks][2][128]  (exclusive carries)
//   [4720640, ...)        Bu fp32 [NB][8192][256]   transposed: [l][p]
constexpr size_t OFF_BMAT = 2048;
constexpr size_t OFF_CMAT = 264192;
constexpr size_t OFF_END  = 526336;
constexpr size_t OFF_CAR  = 2623488;
constexpr size_t HEADB    = 4720640;
constexpr size_t SZ_BU = (size_t)256 * Ln * 4;     // 8388608 per batch
}

typedef __attribute__((ext_vector_type(4))) float f32x4;
typedef __attribute__((ext_vector_type(8))) short bf16x8;
typedef __attribute__((ext_vector_type(4))) short bf16x4;

static __device__ inline short f2bf(float x) {
  __hip_bfloat16 h = __float2bfloat16(x);
  return *(short*)&h;
}

static __device__ inline void async_copy16(const void* g, void* l) {
  __builtin_amdgcn_global_load_lds(
      (const __attribute__((address_space(1))) unsigned int*)g,
      (__attribute__((address_space(3))) unsigned int*)l, 16, 0, 0);
}

// ---------------------------------------------------------------- precompute
__global__ void precompute_kernel(const float* __restrict__ Lre,
                                  const float* __restrict__ Lim,
                                  const float* __restrict__ Bin,
                                  const float* __restrict__ Cin,
                                  const float* __restrict__ lstep,
                                  float* __restrict__ Lam,
                                  __hip_bfloat16* __restrict__ Bmat,
                                  __hip_bfloat16* __restrict__ Cmat) {
  int tid = blockIdx.x * blockDim.x + threadIdx.x;
  if (tid < 2 * Pn * Hn) {
    int r = tid >> 9;          // row in [0,256)
    int h = tid & (Hn - 1);
    int p = r & (Pn - 1);
    float st = expf(lstep[p]);
    float lr = Lre[p], li = Lim[p];
    float er = expf(lr * st);
    float cr = er * cosf(li * st);
    float ci = er * sinf(li * st);
    float nr = cr - 1.0f, ni = ci;
    float inv = 1.0f / (lr * lr + li * li);
    float wr = (nr * lr + ni * li) * inv;
    float wi = (ni * lr - nr * li) * inv;
    float btr = Bin[(p * Hn + h) * 2 + 0];
    float bti = Bin[(p * Hn + h) * 2 + 1];
    float val = (r < Pn) ? (wr * btr - wi * bti) : (wr * bti + wi * btr);
    Bmat[tid] = __float2bfloat16(val);
  } else if (tid < 4 * Pn * Hn) {
    int j = tid - 2 * Pn * Hn;
    int h = j >> 8;
    int c = j & 255;
    int p = c & (Pn - 1);
    float v = (c < Pn) ? 2.0f * Cin[(h * Pn + p) * 2 + 0]
                       : -2.0f * Cin[(h * Pn + p) * 2 + 1];
    Cmat[j] = __float2bfloat16(v);
  } else if (tid < 4 * Pn * Hn + 512) {
    int j = tid - 4 * Pn * Hn;
    int p = j & 127;
    int sel = j >> 7;   // 0: L_re  1: L_im  2: A32_re  3: A32_im
    float st = expf(lstep[p]);
    float lr = Lre[p], li = Lim[p];
    float sc = (sel < 2) ? st : 32.0f * st;
    float er = expf(lr * sc);
    Lam[(sel >> 1) * 256 + (sel & 1) * 128 + p] =
        (sel & 1) ? er * sinf(li * sc) : er * cosf(li * sc);
  }
}

// ---------------------------------------------------------------- MFMA GEMM1 (BM=256 full-M, BN=64)
// Bu_t[bz][l][256] = (Bmat[256][512] @ U[(b0+bz)][512][8192])^T
// Each block owns 64 complete l-rows -> full 1KB row writes, U read exactly once.
__global__ __launch_bounds__(256) void gemm1_kernel(
    const __hip_bfloat16* __restrict__ Amat,  // [256][512]
    const float* __restrict__ U,              // [8][512][8192]
    float* __restrict__ Bu,                   // [NB][8192][256]
    int b0) {
  __shared__ __align__(16) short As[256 * 32];   // 16 KB
  __shared__ __align__(16) short Bs[64 * 40];    // 5 KB (stride 40 shorts)
  const int t = threadIdx.x;
  const int lane = t & 63, w = t >> 6;
  const int n0 = blockIdx.x * 64;
  const int bz = blockIdx.z;
  const float* Ub = U + (size_t)(b0 + bz) * Hn * Ln;

  const int srow = lane >> 2, scol = (lane & 3) * 16;  // A staging: 16 rows x 64B per wave round
  const int bn = t & 63, bkg = t >> 6;                 // B staging: col n, k-octet

  f32x4 acc[4][4] = {};
  for (int k0 = 0; k0 < Hn; k0 += 32) {
    // A: 256 rows x 32k bf16 = 16KB, 4 copy16 rounds per wave
#pragma unroll
    for (int I2 = 0; I2 < 4; I2++) {
      int I = 4 * w + I2;    // 0..15
      async_copy16((const char*)(Amat + (size_t)(16 * I + srow) * Hn + k0) + scol,
                   (char*)As + I * 1024);
    }
    // B: 64 n x 32 k from U[k][n], coalesced scalar loads
    {
      float v[8];
#pragma unroll
      for (int j = 0; j < 8; j++)
        v[j] = Ub[(size_t)(k0 + bkg * 8 + j) * Ln + n0 + bn];
      bf16x8 pk;
#pragma unroll
      for (int j = 0; j < 8; j++) pk[j] = f2bf(v[j]);
      *(bf16x8*)&Bs[bn * 40 + bkg * 8] = pk;
    }
    __syncthreads();
    bf16x8 af[4], bfr[4];
#pragma unroll
    for (int mt = 0; mt < 4; mt++)
      af[mt] = *(const bf16x8*)&As[(64 * w + 16 * mt + (lane & 15)) * 32 + (lane >> 4) * 8];
#pragma unroll
    for (int nt = 0; nt < 4; nt++)
      bfr[nt] = *(const bf16x8*)&Bs[(16 * nt + (lane & 15)) * 40 + (lane >> 4) * 8];
#pragma unroll
    for (int mt = 0; mt < 4; mt++)
#pragma unroll
      for (int nt = 0; nt < 4; nt++)
        acc[mt][nt] = __builtin_amdgcn_mfma_f32_16x16x32_bf16(
            af[mt], bfr[nt], acc[mt][nt], 0, 0, 0);
    __syncthreads();
  }
  // epilogue: lane holds 4 consecutive m (=p) for one n (=l) -> one f32x4 store
  const int row4 = (lane >> 4) * 4, col = lane & 15;
  float* Bub = Bu + (size_t)bz * Ln * 256;
#pragma unroll
  for (int mt = 0; mt < 4; mt++)
#pragma unroll
    for (int nt = 0; nt < 4; nt++) {
      int n = n0 + 16 * nt + col;
      int m = 64 * w + 16 * mt + row4;
      *(f32x4*)&Bub[(size_t)n * 256 + m] = acc[mt][nt];
    }
}

// ---------------------------------------------------------------- scan phase 1: local chunk ends
__global__ __launch_bounds__(256) void scan_ends_kernel(const float* __restrict__ Bu,
                                                        const float* __restrict__ Lam,
                                                        float* __restrict__ End) {
  const int bz = blockIdx.y;
  const int t = threadIdx.x;
  const int c = blockIdx.x * 2 + (t >> 7);
  const int p = t & 127;
  const float Ar = Lam[p], Ai = Lam[128 + p];
  const float* base = Bu + ((size_t)bz * Ln + (size_t)c * 32) * 256;
  float br[32], bi[32];
#pragma unroll
  for (int i = 0; i < 32; i++) br[i] = base[(size_t)i * 256 + p];
#pragma unroll
  for (int i = 0; i < 32; i++) bi[i] = base[(size_t)i * 256 + 128 + p];
  float xr = 0.f, xi = 0.f;
#pragma unroll
  for (int i = 0; i < 32; i++) {
    float nr = fmaf(Ar, xr, fmaf(-Ai, xi, br[i]));
    float ni = fmaf(Ar, xi, fmaf(Ai, xr, bi[i]));
    xr = nr; xi = ni;
  }
  float* E = End + ((size_t)bz * 256 + c) * 256;
  E[p] = xr;
  E[128 + p] = xi;
}

// ---------------------------------------------------------------- scan phase 2: carry propagation
__global__ __launch_bounds__(128) void carry_kernel(const float* __restrict__ End,
                                                    float* __restrict__ Carry,
                                                    const float* __restrict__ Lam) {
  const int bz = blockIdx.x;
  const int p = threadIdx.x;
  const float a32r = Lam[256 + p], a32i = Lam[384 + p];
  const float* E = End + (size_t)bz * 256 * 256;
  float* C = Carry + (size_t)bz * 256 * 256;
  float xr = 0.f, xi = 0.f;
  float er0[4], ei0[4], er1[4], ei1[4];
#pragma unroll
  for (int q = 0; q < 4; q++) {
    er0[q] = E[(size_t)q * 256 + p];
    ei0[q] = E[(size_t)q * 256 + 128 + p];
  }
  for (int c0 = 0; c0 < 256; c0 += 8) {
#pragma unroll
    for (int q = 0; q < 4; q++) {
      er1[q] = E[(size_t)(c0 + 4 + q) * 256 + p];
      ei1[q] = E[(size_t)(c0 + 4 + q) * 256 + 128 + p];
    }
#pragma unroll
    for (int q = 0; q < 4; q++) {
      C[(size_t)(c0 + q) * 256 + p] = xr;
      C[(size_t)(c0 + q) * 256 + 128 + p] = xi;
      float nr = fmaf(a32r, xr, fmaf(-a32i, xi, er0[q]));
      float ni = fmaf(a32r, xi, fmaf(a32i, xr, ei0[q]));
      xr = nr; xi = ni;
    }
#pragma unroll
    for (int q = 0; q < 4; q++) {
      int cn = c0 + 8 + q;
      if (cn < 256) {
        er0[q] = E[(size_t)cn * 256 + p];
        ei0[q] = E[(size_t)cn * 256 + 128 + p];
      }
    }
#pragma unroll
    for (int q = 0; q < 4; q++) {
      C[(size_t)(c0 + 4 + q) * 256 + p] = xr;
      C[(size_t)(c0 + 4 + q) * 256 + 128 + p] = xi;
      float nr = fmaf(a32r, xr, fmaf(-a32i, xi, er1[q]));
      float ni = fmaf(a32r, xi, fmaf(a32i, xr, ei1[q]));
      xr = nr; xi = ni;
    }
  }
}

// ---------------------------------------------------------------- scan phase 3: seeded local scan, in place
__global__ __launch_bounds__(256) void scan_apply_kernel(float* __restrict__ Bu,
                                                         const float* __restrict__ Lam,
                                                         const float* __restrict__ Carry) {
  const int bz = blockIdx.y;
  const int t = threadIdx.x;
  const int c = blockIdx.x * 2 + (t >> 7);
  const int p = t & 127;
  const float Ar = Lam[p], Ai = Lam[128 + p];
  float* base = Bu + ((size_t)bz * Ln + (size_t)c * 32) * 256;
  const float* Cg = Carry + ((size_t)bz * 256 + c) * 256;
  float br[32], bi[32];
#pragma unroll
  for (int i = 0; i < 32; i++) br[i] = base[(size_t)i * 256 + p];
#pragma unroll
  for (int i = 0; i < 32; i++) bi[i] = base[(size_t)i * 256 + 128 + p];
  float xr = Cg[p], xi = Cg[128 + p];
#pragma unroll
  for (int i = 0; i < 32; i++) {
    float nr = fmaf(Ar, xr, fmaf(-Ai, xi, br[i]));
    float ni = fmaf(Ar, xi, fmaf(Ai, xr, bi[i]));
    xr = nr; xi = ni;
    base[(size_t)i * 256 + p] = nr;
    base[(size_t)i * 256 + 128 + p] = ni;
  }
}

// ---------------------------------------------------------------- MFMA GEMM2 (coalesced row-group staging + fast gelu)
// Out[b][H][L] = gelu( Cmat[512][256] @ Xs^T + D[h]*U[b][h][l] ),  Xs = Bu_t[bz][l][256]
__global__ __launch_bounds__(256) void gemm2_kernel(
    const __hip_bfloat16* __restrict__ Cmat,  // [512][256]
    const float* __restrict__ Xs,             // [NB][8192][256] fp32 ([l][p])
    const float* __restrict__ U,              // [8][512][8192]
    const float* __restrict__ Dv,             // [512]
    float* __restrict__ Out, int b0) {
  __shared__ __align__(16) short As[128 * 32];
  __shared__ __align__(16) short Bs[128 * 40];
  const int t = threadIdx.x;
  const int lane = t & 63, w = t >> 6;
  const int wm = w >> 1, wn = w & 1;
  const int n0 = blockIdx.x * 128;
  const int m0 = blockIdx.y * 128;
  const int bz = blockIdx.z;
  const int b = b0 + bz;

  const int srow = lane >> 2, scol = (lane & 3) * 16;
  // B staging: 4 lanes cooperatively read one row's 128B k-window (fully coalesced)
  const int krow = t >> 2;   // 0..63: row within 64-row round
  const int kq = t & 3;      // 0..3: 16B sub-chunk
  const float* Xbase = Xs + ((size_t)bz * Ln + n0) * 256;

  f32x4 acc[4][4] = {};
  for (int k0 = 0; k0 < 256; k0 += 32) {
#pragma unroll
    for (int I2 = 0; I2 < 2; I2++) {
      int I = 2 * w + I2;
      async_copy16((const char*)(Cmat + (size_t)(m0 + 16 * I + srow) * 256 + k0) + scol,
                   (char*)As + I * 1024);
    }
#pragma unroll
    for (int ro = 0; ro < 2; ro++) {
      int row = ro * 64 + krow;
      const float* src = Xbase + (size_t)row * 256 + k0 + kq * 4;
      f32x4 x0 = *(const f32x4*)src;          // k = k0+kq*4 .. +4
      f32x4 x1 = *(const f32x4*)(src + 16);   // k = k0+16+kq*4 .. +4
      bf16x4 a, c;
#pragma unroll
      for (int q = 0; q < 4; q++) { a[q] = f2bf(x0[q]); c[q] = f2bf(x1[q]); }
      *(bf16x4*)&Bs[row * 40 + kq * 4] = a;
      *(bf16x4*)&Bs[row * 40 + 16 + kq * 4] = c;
    }
    __syncthreads();
    bf16x8 af[4], bfr[4];
#pragma unroll
    for (int mt = 0; mt < 4; mt++)
      af[mt] = *(const bf16x8*)&As[(64 * wm + 16 * mt + (lane & 15)) * 32 + (lane >> 4) * 8];
#pragma unroll
    for (int nt = 0; nt < 4; nt++)
      bfr[nt] = *(const bf16x8*)&Bs[(64 * wn + 16 * nt + (lane & 15)) * 40 + (lane >> 4) * 8];
#pragma unroll
    for (int mt = 0; mt < 4; mt++)
#pragma unroll
      for (int nt = 0; nt < 4; nt++)
        acc[mt][nt] = __builtin_amdgcn_mfma_f32_16x16x32_bf16(
            af[mt], bfr[nt], acc[mt][nt], 0, 0, 0);
    __syncthreads();
  }
  const int row4 = (lane >> 4) * 4, col = lane & 15;
#pragma unroll
  for (int mt = 0; mt < 4; mt++) {
#pragma unroll
    for (int r = 0; r < 4; r++) {
      int h = m0 + 64 * wm + 16 * mt + row4 + r;
      float dh = Dv[h];
      const float* Urow = U + ((size_t)b * Hn + h) * Ln;
      float* Orow = Out + ((size_t)b * Hn + h) * Ln;
#pragma unroll
      for (int nt = 0; nt < 4; nt++) {
        int n = n0 + 64 * wn + 16 * nt + col;
        float y = acc[mt][nt][r] + dh * Urow[n];
        // tanh-form gelu: y * sigmoid(2*0.7978845608*(y + 0.044715 y^3)), tail-safe
        float u2 = y * (0.7978845608f + 0.0356774081f * y * y);
        Orow[n] = y / (1.0f + __expf(-2.0f * u2));
      }
    }
  }
}

// ---------------------------------------------------------------- launch
extern "C" void kernel_launch(void* const* d_in, const int* in_sizes, int n_in,
                              void* d_out, int out_size, void* d_ws, size_t ws_size,
                              hipStream_t stream) {
  const float* U   = (const float*)d_in[0];
  const float* Lre = (const float*)d_in[1];
  const float* Lim = (const float*)d_in[2];
  const float* Bin = (const float*)d_in[3];
  const float* Cin = (const float*)d_in[4];
  const float* Dv  = (const float*)d_in[5];
  const float* ls  = (const float*)d_in[6];
  float* out = (float*)d_out;

  char* wsb = (char*)d_ws;
  float* Lam = (float*)wsb;
  __hip_bfloat16* Bmat = (__hip_bfloat16*)(wsb + OFF_BMAT);
  __hip_bfloat16* Cmat = (__hip_bfloat16*)(wsb + OFF_CMAT);
  float* End = (float*)(wsb + OFF_END);
  float* Cy  = (float*)(wsb + OFF_CAR);
  float* Bu  = (float*)(wsb + HEADB);

  int NB = 8;
  while (NB > 1 && ws_size < HEADB + (size_t)NB * SZ_BU)
    NB >>= 1;

  precompute_kernel<<<(4 * Pn * Hn + 512 + 255) / 256, 256, 0, stream>>>(
      Lre, Lim, Bin, Cin, ls, Lam, Bmat, Cmat);

  for (int b0 = 0; b0 < BS; b0 += NB) {
    gemm1_kernel<<<dim3(Ln / 64, 1, NB), 256, 0, stream>>>(Bmat, U, Bu, b0);
    scan_ends_kernel<<<dim3(128, NB), 256, 0, stream>>>(Bu, Lam, End);
    carry_kernel<<<dim3(NB), 128, 0, stream>>>(End, Cy, Lam);
    scan_apply_kernel<<<dim3(128, NB), 256, 0, stream>>>(Bu, Lam, Cy);
    gemm2_kernel<<<dim3(Ln / 128, Hn / 128, NB), 256, 0, stream>>>(
        Cmat, Bu, U, Dv, out, b0);
  }
}